// Round 9
// baseline (252.473 us; speedup 1.0000x reference)
//
#include <hip/hip_runtime.h>
#include <hip/hip_bf16.h>
#include <math.h>

#define D_MODEL 512
#define N_HEADS 8
#define HEAD_DIM 64
#define BATCH 2
#define SEQ 4096
#define M_ROWS (BATCH*SEQ)   // 8192

typedef __attribute__((ext_vector_type(8))) short short8;
typedef __attribute__((ext_vector_type(4))) float f32x4;

__device__ inline short f2bf(float f) {
  union { float f; unsigned u; } v; v.f = f;
  unsigned u = v.u;
  unsigned r = u + 0x7FFFu + ((u >> 16) & 1u);
  return (short)(r >> 16);
}
__device__ inline float bf2f(short s) {
  union { unsigned u; float f; } v; v.u = ((unsigned)(unsigned short)s) << 16;
  return v.f;
}

__device__ inline void gll16(const void* g, void* l) {
  __builtin_amdgcn_global_load_lds(
      (const __attribute__((address_space(1))) unsigned int*)g,
      (__attribute__((address_space(3))) unsigned int*)l, 16, 0, 0);
}

// ---------------- prep: casts + rope tables ----------------
__global__ void prep_kernel(const float* __restrict__ x,
                            const float* __restrict__ Wq,
                            const float* __restrict__ Wk,
                            const float* __restrict__ Wv,
                            const float* __restrict__ Wo,
                            short* __restrict__ xb,
                            short* __restrict__ Wqkv,
                            short* __restrict__ Wob,
                            float* __restrict__ cosT,
                            float* __restrict__ sinT) {
  int i = blockIdx.x * blockDim.x + threadIdx.x;
  if (i < M_ROWS * D_MODEL) xb[i] = f2bf(x[i]);
  if (i < 3 * D_MODEL * D_MODEL) {
    int t = i >> 18;
    int r = i & 262143;
    const float* W = (t == 0) ? Wq : ((t == 1) ? Wk : Wv);
    Wqkv[i] = f2bf(W[r]);
  }
  if (i < D_MODEL * D_MODEL) Wob[i] = f2bf(Wo[i]);
  if (i < SEQ * 32) {
    int s = i >> 5, p = i & 31;
    float e = (float)(2 * p) * (1.0f / 64.0f);
    float inv = powf(10000.0f, -e);
    float ang = (float)s * inv;
    float sv, cv;
    sincosf(ang, &sv, &cv);
    cosT[i] = cv; sinT[i] = sv;
  }
}

// ---------------- GEMM with fp32-RoPE + LDS-coalesced epilogue ----------------
// MODE 0: N=1536 fused QKV; RoPE applied to Q/K in fp32 registers (lane^1
//         shuffle partner), then bf16 -> LDS -> fully coalesced 16B stores.
//         Q/K [BH][S][64]; Vt [BH][64][S].
// MODE 1: N=512 -> fp32 d_out (direct store, line-coalesced)
template<int MODE>
__global__ __launch_bounds__(256) void gemm_kernel(const short* __restrict__ A,
                                                   const short* __restrict__ B,
                                                   float* __restrict__ out_f,
                                                   short* __restrict__ Qb,
                                                   short* __restrict__ Kb,
                                                   short* __restrict__ Vb,
                                                   const float* __restrict__ cosT,
                                                   const float* __restrict__ sinT) {
  __shared__ short smem[128 * 72 * 2];           // 36864 B, reused by epilogue
  short (*As)[72] = (short(*)[72])smem;
  short (*Bs)[72] = (short(*)[72])(smem + 128 * 72);
  short (*Cs)[136] = (short(*)[136])smem;        // 17408 shorts <= 18432*2

  const int m0 = blockIdx.x * 128;
  const int n0 = blockIdx.y * 128;
  const int tid = threadIdx.x;
  const int lane = tid & 63, wid = tid >> 6;
  const int wm = wid >> 1, wn = wid & 1;
  const int l15 = lane & 15, g = lane >> 4;
  const int Kdim = 512;

  f32x4 acc[4][4] = {};

  for (int kt = 0; kt < Kdim; kt += 64) {
    __syncthreads();
    for (int it = 0; it < 4; ++it) {
      int c = it * 256 + tid;
      int row = c >> 3, col = (c & 7) << 3;
      *(short8*)&As[row][col] = *(const short8*)&A[(m0 + row) * Kdim + kt + col];
      *(short8*)&Bs[row][col] = *(const short8*)&B[(n0 + row) * Kdim + kt + col];
    }
    __syncthreads();
    for (int kk = 0; kk < 64; kk += 32) {
      short8 a[4], b[4];
      for (int mi = 0; mi < 4; ++mi)
        a[mi] = *(const short8*)&As[wm * 64 + mi * 16 + l15][kk + (g << 3)];
      for (int ni = 0; ni < 4; ++ni)
        b[ni] = *(const short8*)&Bs[wn * 64 + ni * 16 + l15][kk + (g << 3)];
      for (int mi = 0; mi < 4; ++mi)
        for (int ni = 0; ni < 4; ++ni)
          acc[mi][ni] = __builtin_amdgcn_mfma_f32_16x16x32_bf16(a[mi], b[ni], acc[mi][ni], 0, 0, 0);
    }
  }

  if (MODE == 1) {
    for (int mi = 0; mi < 4; ++mi)
      for (int ni = 0; ni < 4; ++ni)
        for (int r = 0; r < 4; ++r) {
          int row_g = m0 + wm * 64 + mi * 16 + (g << 2) + r;
          int col_g = n0 + wn * 64 + ni * 16 + l15;
          out_f[row_g * 512 + col_g] = acc[mi][ni][r];
        }
    return;
  }

  // ---- MODE 0 epilogue ----
  const int t_blk = n0 >> 9;   // 0:Q 1:K 2:V (uniform per block)
  __syncthreads();             // main loop's As/Bs reads done before overwrite

  if (t_blk < 2) {
    // RoPE in fp32 BEFORE any bf16 rounding (partner = adjacent d = lane^1)
    const float qs = (t_blk == 0) ? 0.18033688011112042f : 1.0f;  // 0.125*log2e
    for (int mi = 0; mi < 4; ++mi)
      for (int ni = 0; ni < 4; ++ni)
        for (int r = 0; r < 4; ++r) {
          int lrow = wm * 64 + mi * 16 + (g << 2) + r;
          int ss = (m0 + lrow) & 4095;
          int d = (n0 + wn * 64 + ni * 16 + l15) & 63;
          int p = d >> 1;
          float c = cosT[ss * 32 + p], s = sinT[ss * 32 + p];
          float v = acc[mi][ni][r];
          float partner = __shfl_xor(v, 1);
          float res = (l15 & 1) ? (v * c + partner * s) : (v * c - partner * s);
          Cs[lrow][wn * 64 + ni * 16 + l15] = f2bf(res * qs);
        }
  } else {
    for (int mi = 0; mi < 4; ++mi)
      for (int ni = 0; ni < 4; ++ni)
        for (int r = 0; r < 4; ++r)
          Cs[wm * 64 + mi * 16 + (g << 2) + r][wn * 64 + ni * 16 + l15] =
              f2bf(acc[mi][ni][r]);
  }
  __syncthreads();

  if (t_blk < 2) {
    short* dst = (t_blk == 0) ? Qb : Kb;
#pragma unroll
    for (int it = 0; it < 8; ++it) {
      int row = (tid >> 4) + (it << 4);           // 0..127
      int colb = (tid & 15) << 3;                 // 0..120 (8 cols)
      short8 vv = *(const short8*)&Cs[row][colb];
      int row_g = m0 + row;
      int ss = row_g & 4095, bb = row_g >> 12;
      int cc = (n0 + colb) & 511;
      int h = cc >> 6, d = cc & 63;               // d multiple of 8
      *(short8*)&dst[(((bb << 3) + h) * SEQ + ss) * 64 + d] = vv;
    }
  } else {
#pragma unroll
    for (int it = 0; it < 8; ++it) {
      int c = tid & 127;                               // output d-col
      int sb = ((tid >> 7) << 3) + (it << 4);          // ss block of 8
      short8 o8;
#pragma unroll
      for (int j = 0; j < 8; ++j) o8[j] = Cs[sb + j][c];
      int row_g0 = m0 + sb;
      int ss = row_g0 & 4095, bb = row_g0 >> 12;
      int cc = (n0 + c) & 511;
      int h = cc >> 6, d = cc & 63;
      *(short8*)&Vb[((long)(((bb << 3) + h) * 64 + d)) * SEQ + ss] = o8;
    }
  }
}

// ---------------- flash attention (causal), LDS-staged + 2-phase ----------------
// Q,K: bf16 [BH=16][S=4096][64] (Q pre-scaled by 0.125*log2e)
// Vt:  bf16 [BH=16][64][S=4096]
// O:   bf16 [B*S=8192][512] (col = h*64+d)
// Grid 512 (2 blocks/CU): block o -> bh = o&15, one 128-row tile:
//   o<256: tile = 31-(o>>4) (longest first); o>=256: tile = (o>>4)-16.
//   Complementary pairs (o, o+256) sum to 66 chunk-iters per CU.
__global__ __launch_bounds__(512, 4) void attn_kernel(const short* __restrict__ Q,
                                                      const short* __restrict__ K,
                                                      const short* __restrict__ Vt,
                                                      short* __restrict__ O) {
  __shared__ short Ks[2][64 * 64];
  __shared__ short Vs[2][64 * 64];
  __shared__ short P_lds[8][16][72];

  const int o = blockIdx.x;
  const int j = o >> 4;                        // 0..31
  const int bh = o & 15;
  const int tile = (o < 256) ? (31 - j) : (j - 16);

  const int tid = threadIdx.x, lane = tid & 63, w = tid >> 6;
  const int l15 = lane & 15, g = lane >> 4;
  const long base = (long)bh * SEQ * 64;
  const long baseV = (long)bh * 64 * SEQ;
  const int bb = bh >> 3, h = bh & 7;

  const int srow = tid >> 3;                      // 0..63
  const int sc16k = (tid & 7) ^ (srow & 7);       // swizzled 16B-block column
  short* ldsSegK0 = &Ks[0][(tid >> 6) << 9];
  short* ldsSegK1 = &Ks[1][(tid >> 6) << 9];
  short* ldsSegV0 = &Vs[0][(tid >> 6) << 9];
  short* ldsSegV1 = &Vs[1][(tid >> 6) << 9];

  const int q0 = (tile << 7) + (w << 4);
  const int nc = 2 * tile + 2;

  short8 aq0 = *(const short8*)&Q[base + (long)(q0 + l15) * 64 + (g << 3)];
  short8 aq1 = *(const short8*)&Q[base + (long)(q0 + l15) * 64 + 32 + (g << 3)];

  f32x4 o_acc[4] = {};
  float m_r[4], l_r[4];
#pragma unroll
  for (int r = 0; r < 4; ++r) { m_r[r] = -__builtin_inff(); l_r[r] = 0.f; }

  // prologue: stage chunk 0 -> buf 0
  gll16(&K[base + (long)srow * 64 + sc16k * 8], ldsSegK0);
  gll16(&Vt[baseV + (long)srow * SEQ + sc16k * 8], ldsSegV0);

  for (int c = 0; c < nc; ++c) {
    const int kv0 = c << 6;
    const int bi = c & 1;
    __syncthreads();   // stage(c) complete + prev reads of other buffer done
    if (c + 1 < nc) {
      const int nkv = (c + 1) << 6;
      short* dK = (bi ? ldsSegK0 : ldsSegK1);
      short* dV = (bi ? ldsSegV0 : ldsSegV1);
      gll16(&K[base + (long)(nkv + srow) * 64 + sc16k * 8], dK);
      gll16(&Vt[baseV + (long)srow * SEQ + nkv + sc16k * 8], dV);
    }
    if (kv0 > q0) continue;

    // ---- QK^T from LDS (swizzled reads) ----
    f32x4 sf[4] = {};
    __builtin_amdgcn_s_setprio(1);
#pragma unroll
    for (int f = 0; f < 4; ++f) {
      int row = f * 16 + l15, sw = row & 7;
      short8 bk0 = *(const short8*)&Ks[bi][row * 64 + ((g) ^ sw) * 8];
      short8 bk1 = *(const short8*)&Ks[bi][row * 64 + ((4 + g) ^ sw) * 8];
      sf[f] = __builtin_amdgcn_mfma_f32_16x16x32_bf16(aq0, bk0, sf[f], 0, 0, 0);
      sf[f] = __builtin_amdgcn_mfma_f32_16x16x32_bf16(aq1, bk1, sf[f], 0, 0, 0);
    }
    __builtin_amdgcn_s_setprio(0);
    if (kv0 == (q0 & ~63)) {   // diagonal chunk: causal mask
#pragma unroll
      for (int f = 0; f < 4; ++f) {
        int kvc = kv0 + f * 16 + l15;
#pragma unroll
        for (int r = 0; r < 4; ++r) {
          int qrow = q0 + (g << 2) + r;
          if (kvc > qrow) sf[f][r] = -__builtin_inff();
        }
      }
    }

    // ---- online softmax ----
    float pm[4];
#pragma unroll
    for (int r = 0; r < 4; ++r)
      pm[r] = fmaxf(fmaxf(sf[0][r], sf[1][r]), fmaxf(sf[2][r], sf[3][r]));
#pragma unroll
    for (int off = 1; off < 16; off <<= 1)
#pragma unroll
      for (int r = 0; r < 4; ++r)
        pm[r] = fmaxf(pm[r], __shfl_xor(pm[r], off));

    float pr[4][4], rs[4];
#pragma unroll
    for (int r = 0; r < 4; ++r) {
      float mn = fmaxf(m_r[r], pm[r]);
      float alpha = exp2f(m_r[r] - mn);
      m_r[r] = mn;
      l_r[r] *= alpha;
      float s0 = 0.f;
#pragma unroll
      for (int f = 0; f < 4; ++f) {
        float pv = exp2f(sf[f][r] - mn);
        pr[f][r] = pv;
        s0 += pv;
      }
      rs[r] = s0;
#pragma unroll
      for (int db = 0; db < 4; ++db) o_acc[db][r] *= alpha;
    }
#pragma unroll
    for (int off = 1; off < 16; off <<= 1)
#pragma unroll
      for (int r = 0; r < 4; ++r)
        rs[r] += __shfl_xor(rs[r], off);
#pragma unroll
    for (int r = 0; r < 4; ++r) l_r[r] += rs[r];

    // ---- P -> LDS -> A-fragment ----
#pragma unroll
    for (int f = 0; f < 4; ++f)
#pragma unroll
      for (int r = 0; r < 4; ++r)
        P_lds[w][(g << 2) + r][f * 16 + l15] = f2bf(pr[f][r]);

    short8 pa0 = *(const short8*)&P_lds[w][l15][(g << 3)];
    short8 pa1 = *(const short8*)&P_lds[w][l15][32 + (g << 3)];

    // ---- PV from LDS (swizzled reads) ----
    __builtin_amdgcn_s_setprio(1);
#pragma unroll
    for (int kk = 0; kk < 2; ++kk) {
      short8 pa = kk ? pa1 : pa0;
#pragma unroll
      for (int db = 0; db < 4; ++db) {
        int row = db * 16 + l15, sw = row & 7;
        short8 bv = *(const short8*)&Vs[bi][row * 64 + ((kk * 4 + g) ^ sw) * 8];
        o_acc[db] = __builtin_amdgcn_mfma_f32_16x16x32_bf16(pa, bv, o_acc[db], 0, 0, 0);
      }
    }
    __builtin_amdgcn_s_setprio(0);
  }

  // ---- epilogue: write O ----
#pragma unroll
  for (int db = 0; db < 4; ++db)
#pragma unroll
    for (int r = 0; r < 4; ++r) {
      int s_g = q0 + (g << 2) + r;
      float v = o_acc[db][r] / l_r[r];
      O[((long)(bb * SEQ + s_g)) * 512 + h * 64 + db * 16 + l15] = f2bf(v);
    }
}

extern "C" void kernel_launch(void* const* d_in, const int* in_sizes, int n_in,
                              void* d_out, int out_size, void* d_ws, size_t ws_size,
                              hipStream_t stream) {
  const float* x  = (const float*)d_in[0];
  const float* Wq = (const float*)d_in[1];
  const float* Wk = (const float*)d_in[2];
  const float* Wv = (const float*)d_in[3];
  const float* Wo = (const float*)d_in[4];

  char* ws = (char*)d_ws;
  size_t off = 0;
  auto alloc = [&](size_t bytes) {
    void* p = ws + off;
    off += (bytes + 255) & ~(size_t)255;
    return p;
  };
  short* xb   = (short*)alloc((size_t)M_ROWS * 512 * 2);
  short* Wqkv = (short*)alloc((size_t)1536 * 512 * 2);
  short* Wob  = (short*)alloc((size_t)512 * 512 * 2);
  float* cosT = (float*)alloc((size_t)SEQ * 32 * 4);
  float* sinT = (float*)alloc((size_t)SEQ * 32 * 4);
  short* Qb   = (short*)alloc((size_t)16 * SEQ * 64 * 2);
  short* Kb   = (short*)alloc((size_t)16 * SEQ * 64 * 2);
  short* Vt   = (short*)alloc((size_t)16 * SEQ * 64 * 2);
  short* Obuf = (short*)alloc((size_t)M_ROWS * 512 * 2);

  prep_kernel<<<16384, 256, 0, stream>>>(x, Wq, Wk, Wv, Wo, xb, Wqkv, Wob, cosT, sinT);
  gemm_kernel<0><<<dim3(64, 12), 256, 0, stream>>>(xb, Wqkv, nullptr, Qb, Kb, Vt, cosT, sinT);
  attn_kernel<<<512, 512, 0, stream>>>(Qb, Kb, Vt, Obuf);
  gemm_kernel<1><<<dim3(64, 4), 256, 0, stream>>>(Obuf, Wob, (float*)d_out, nullptr, nullptr, nullptr, nullptr, nullptr);
}

// Round 10
// 208.088 us; speedup vs baseline: 1.2133x; 1.2133x over previous
//
#include <hip/hip_runtime.h>
#include <hip/hip_bf16.h>
#include <math.h>

#define D_MODEL 512
#define N_HEADS 8
#define HEAD_DIM 64
#define BATCH 2
#define SEQ 4096
#define M_ROWS (BATCH*SEQ)   // 8192

typedef __attribute__((ext_vector_type(8))) short short8;
typedef __attribute__((ext_vector_type(4))) float f32x4;

__device__ inline short f2bf(float f) {
  union { float f; unsigned u; } v; v.f = f;
  unsigned u = v.u;
  unsigned r = u + 0x7FFFu + ((u >> 16) & 1u);
  return (short)(r >> 16);
}
__device__ inline float bf2f(short s) {
  union { unsigned u; float f; } v; v.u = ((unsigned)(unsigned short)s) << 16;
  return v.f;
}

__device__ inline void gll16(const void* g, void* l) {
  __builtin_amdgcn_global_load_lds(
      (const __attribute__((address_space(1))) unsigned int*)g,
      (__attribute__((address_space(3))) unsigned int*)l, 16, 0, 0);
}

__device__ inline short8 cvt8(float4 a, float4 b) {
  short8 o;
  o[0] = f2bf(a.x); o[1] = f2bf(a.y); o[2] = f2bf(a.z); o[3] = f2bf(a.w);
  o[4] = f2bf(b.x); o[5] = f2bf(b.y); o[6] = f2bf(b.z); o[7] = f2bf(b.w);
  return o;
}

// ---------------- prep: vectorized casts + rope tables ----------------
#define XOCT (M_ROWS*D_MODEL/8)      // 524288
#define WOCT (3*D_MODEL*D_MODEL/8)   // 98304
#define OOCT (D_MODEL*D_MODEL/8)     // 32768
__global__ void prep_kernel(const float* __restrict__ x,
                            const float* __restrict__ Wq,
                            const float* __restrict__ Wk,
                            const float* __restrict__ Wv,
                            const float* __restrict__ Wo,
                            short* __restrict__ xb,
                            short* __restrict__ Wqkv,
                            short* __restrict__ Wob,
                            float* __restrict__ cosT,
                            float* __restrict__ sinT) {
  int i = blockIdx.x * blockDim.x + threadIdx.x;
  if (i < XOCT) {
    float4 a = *(const float4*)&x[i * 8];
    float4 b = *(const float4*)&x[i * 8 + 4];
    *(short8*)&xb[i * 8] = cvt8(a, b);
  }
  if (i < WOCT) {
    int e = i * 8;
    int t = e >> 18, r = e & 262143;
    const float* W = (t == 0) ? Wq : ((t == 1) ? Wk : Wv);
    float4 a = *(const float4*)&W[r];
    float4 b = *(const float4*)&W[r + 4];
    *(short8*)&Wqkv[e] = cvt8(a, b);
  }
  if (i < OOCT) {
    float4 a = *(const float4*)&Wo[i * 8];
    float4 b = *(const float4*)&Wo[i * 8 + 4];
    *(short8*)&Wob[i * 8] = cvt8(a, b);
  }
  if (i < SEQ * 32) {
    int s = i >> 5, p = i & 31;
    float e = (float)(2 * p) * (1.0f / 64.0f);
    float inv = powf(10000.0f, -e);
    float ang = (float)s * inv;
    float sv, cv;
    sincosf(ang, &sv, &cv);
    cosT[i] = cv; sinT[i] = sv;
  }
}

// ---------------- GEMM with fp32-RoPE + LDS-coalesced epilogue ----------------
// MODE 0: N=1536 fused QKV; RoPE applied to Q/K in fp32 registers (lane^1
//         shuffle partner), then bf16 -> LDS -> fully coalesced 16B stores.
//         Q/K [BH][S][64]; Vt [BH][64][S].
// MODE 1: N=512 -> fp32 d_out (direct store, line-coalesced)
template<int MODE>
__global__ __launch_bounds__(256) void gemm_kernel(const short* __restrict__ A,
                                                   const short* __restrict__ B,
                                                   float* __restrict__ out_f,
                                                   short* __restrict__ Qb,
                                                   short* __restrict__ Kb,
                                                   short* __restrict__ Vb,
                                                   const float* __restrict__ cosT,
                                                   const float* __restrict__ sinT) {
  __shared__ short smem[128 * 72 * 2];           // 36864 B, reused by epilogue
  short (*As)[72] = (short(*)[72])smem;
  short (*Bs)[72] = (short(*)[72])(smem + 128 * 72);
  short (*Cs)[136] = (short(*)[136])smem;        // 17408 shorts <= 18432*2

  const int m0 = blockIdx.x * 128;
  const int n0 = blockIdx.y * 128;
  const int tid = threadIdx.x;
  const int lane = tid & 63, wid = tid >> 6;
  const int wm = wid >> 1, wn = wid & 1;
  const int l15 = lane & 15, g = lane >> 4;
  const int Kdim = 512;

  f32x4 acc[4][4] = {};

  for (int kt = 0; kt < Kdim; kt += 64) {
    __syncthreads();
    for (int it = 0; it < 4; ++it) {
      int c = it * 256 + tid;
      int row = c >> 3, col = (c & 7) << 3;
      *(short8*)&As[row][col] = *(const short8*)&A[(m0 + row) * Kdim + kt + col];
      *(short8*)&Bs[row][col] = *(const short8*)&B[(n0 + row) * Kdim + kt + col];
    }
    __syncthreads();
    for (int kk = 0; kk < 64; kk += 32) {
      short8 a[4], b[4];
      for (int mi = 0; mi < 4; ++mi)
        a[mi] = *(const short8*)&As[wm * 64 + mi * 16 + l15][kk + (g << 3)];
      for (int ni = 0; ni < 4; ++ni)
        b[ni] = *(const short8*)&Bs[wn * 64 + ni * 16 + l15][kk + (g << 3)];
      for (int mi = 0; mi < 4; ++mi)
        for (int ni = 0; ni < 4; ++ni)
          acc[mi][ni] = __builtin_amdgcn_mfma_f32_16x16x32_bf16(a[mi], b[ni], acc[mi][ni], 0, 0, 0);
    }
  }

  if (MODE == 1) {
    for (int mi = 0; mi < 4; ++mi)
      for (int ni = 0; ni < 4; ++ni)
        for (int r = 0; r < 4; ++r) {
          int row_g = m0 + wm * 64 + mi * 16 + (g << 2) + r;
          int col_g = n0 + wn * 64 + ni * 16 + l15;
          out_f[row_g * 512 + col_g] = acc[mi][ni][r];
        }
    return;
  }

  // ---- MODE 0 epilogue ----
  const int t_blk = n0 >> 9;   // 0:Q 1:K 2:V (uniform per block)
  __syncthreads();             // main loop's As/Bs reads done before overwrite

  if (t_blk < 2) {
    // RoPE in fp32 BEFORE any bf16 rounding (partner = adjacent d = lane^1)
    const float qs = (t_blk == 0) ? 0.18033688011112042f : 1.0f;  // 0.125*log2e
    for (int mi = 0; mi < 4; ++mi)
      for (int ni = 0; ni < 4; ++ni)
        for (int r = 0; r < 4; ++r) {
          int lrow = wm * 64 + mi * 16 + (g << 2) + r;
          int ss = (m0 + lrow) & 4095;
          int d = (n0 + wn * 64 + ni * 16 + l15) & 63;
          int p = d >> 1;
          float c = cosT[ss * 32 + p], s = sinT[ss * 32 + p];
          float v = acc[mi][ni][r];
          float partner = __shfl_xor(v, 1);
          float res = (l15 & 1) ? (v * c + partner * s) : (v * c - partner * s);
          Cs[lrow][wn * 64 + ni * 16 + l15] = f2bf(res * qs);
        }
  } else {
    for (int mi = 0; mi < 4; ++mi)
      for (int ni = 0; ni < 4; ++ni)
        for (int r = 0; r < 4; ++r)
          Cs[wm * 64 + mi * 16 + (g << 2) + r][wn * 64 + ni * 16 + l15] =
              f2bf(acc[mi][ni][r]);
  }
  __syncthreads();

  if (t_blk < 2) {
    short* dst = (t_blk == 0) ? Qb : Kb;
#pragma unroll
    for (int it = 0; it < 8; ++it) {
      int row = (tid >> 4) + (it << 4);           // 0..127
      int colb = (tid & 15) << 3;                 // 0..120 (8 cols)
      short8 vv = *(const short8*)&Cs[row][colb];
      int row_g = m0 + row;
      int ss = row_g & 4095, bb = row_g >> 12;
      int cc = (n0 + colb) & 511;
      int h = cc >> 6, d = cc & 63;               // d multiple of 8
      *(short8*)&dst[(((bb << 3) + h) * SEQ + ss) * 64 + d] = vv;
    }
  } else {
#pragma unroll
    for (int it = 0; it < 8; ++it) {
      int c = tid & 127;                               // output d-col
      int sb = ((tid >> 7) << 3) + (it << 4);          // ss block of 8
      short8 o8;
#pragma unroll
      for (int j = 0; j < 8; ++j) o8[j] = Cs[sb + j][c];
      int row_g0 = m0 + sb;
      int ss = row_g0 & 4095, bb = row_g0 >> 12;
      int cc = (n0 + c) & 511;
      int h = cc >> 6, d = cc & 63;
      *(short8*)&Vb[((long)(((bb << 3) + h) * 64 + d)) * SEQ + ss] = o8;
    }
  }
}

// ---------------- flash attention (causal), LDS-staged + 2-phase ----------------
// Q,K: bf16 [BH=16][S=4096][64] (Q pre-scaled by 0.125*log2e)
// Vt:  bf16 [BH=16][64][S=4096]
// O:   bf16 [B*S=8192][512] (col = h*64+d)
// Grid 512 (2 blocks/CU). T13 defer-max: per-chunk cross-lane reduces removed
// from the common path; l_r kept as per-lane partials, reduced once at the end.
__global__ __launch_bounds__(512, 4) void attn_kernel(const short* __restrict__ Q,
                                                      const short* __restrict__ K,
                                                      const short* __restrict__ Vt,
                                                      short* __restrict__ O) {
  __shared__ short Ks[2][64 * 64];
  __shared__ short Vs[2][64 * 64];
  __shared__ short P_lds[8][16][72];

  const int o = blockIdx.x;
  const int j = o >> 4;                        // 0..31
  const int bh = o & 15;
  const int tile = (o < 256) ? (31 - j) : (j - 16);

  const int tid = threadIdx.x, lane = tid & 63, w = tid >> 6;
  const int l15 = lane & 15, g = lane >> 4;
  const long base = (long)bh * SEQ * 64;
  const long baseV = (long)bh * 64 * SEQ;
  const int bb = bh >> 3, h = bh & 7;

  const int srow = tid >> 3;                      // 0..63
  const int sc16k = (tid & 7) ^ (srow & 7);       // swizzled 16B-block column
  short* ldsSegK0 = &Ks[0][(tid >> 6) << 9];
  short* ldsSegK1 = &Ks[1][(tid >> 6) << 9];
  short* ldsSegV0 = &Vs[0][(tid >> 6) << 9];
  short* ldsSegV1 = &Vs[1][(tid >> 6) << 9];

  const int q0 = (tile << 7) + (w << 4);
  const int nc = 2 * tile + 2;

  short8 aq0 = *(const short8*)&Q[base + (long)(q0 + l15) * 64 + (g << 3)];
  short8 aq1 = *(const short8*)&Q[base + (long)(q0 + l15) * 64 + 32 + (g << 3)];

  f32x4 o_acc[4] = {};
  float m_r[4], l_r[4];
#pragma unroll
  for (int r = 0; r < 4; ++r) { m_r[r] = -__builtin_inff(); l_r[r] = 0.f; }

  // prologue: stage chunk 0 -> buf 0
  gll16(&K[base + (long)srow * 64 + sc16k * 8], ldsSegK0);
  gll16(&Vt[baseV + (long)srow * SEQ + sc16k * 8], ldsSegV0);

  for (int c = 0; c < nc; ++c) {
    const int kv0 = c << 6;
    const int bi = c & 1;
    __syncthreads();   // stage(c) complete + prev reads of other buffer done
    if (c + 1 < nc) {
      const int nkv = (c + 1) << 6;
      short* dK = (bi ? ldsSegK0 : ldsSegK1);
      short* dV = (bi ? ldsSegV0 : ldsSegV1);
      gll16(&K[base + (long)(nkv + srow) * 64 + sc16k * 8], dK);
      gll16(&Vt[baseV + (long)srow * SEQ + nkv + sc16k * 8], dV);
    }
    if (kv0 > q0) continue;

    // ---- QK^T from LDS (swizzled reads) ----
    f32x4 sf[4] = {};
    __builtin_amdgcn_s_setprio(1);
#pragma unroll
    for (int f = 0; f < 4; ++f) {
      int row = f * 16 + l15, sw = row & 7;
      short8 bk0 = *(const short8*)&Ks[bi][row * 64 + ((g) ^ sw) * 8];
      short8 bk1 = *(const short8*)&Ks[bi][row * 64 + ((4 + g) ^ sw) * 8];
      sf[f] = __builtin_amdgcn_mfma_f32_16x16x32_bf16(aq0, bk0, sf[f], 0, 0, 0);
      sf[f] = __builtin_amdgcn_mfma_f32_16x16x32_bf16(aq1, bk1, sf[f], 0, 0, 0);
    }
    __builtin_amdgcn_s_setprio(0);
    if (kv0 == (q0 & ~63)) {   // diagonal chunk: causal mask
#pragma unroll
      for (int f = 0; f < 4; ++f) {
        int kvc = kv0 + f * 16 + l15;
#pragma unroll
        for (int r = 0; r < 4; ++r) {
          int qrow = q0 + (g << 2) + r;
          if (kvc > qrow) sf[f][r] = -__builtin_inff();
        }
      }
    }

    // ---- online softmax, defer-max (T13): no cross-lane ops in common path ----
    float pmx[4];
#pragma unroll
    for (int r = 0; r < 4; ++r)
      pmx[r] = fmaxf(fmaxf(sf[0][r], sf[1][r]), fmaxf(sf[2][r], sf[3][r]));
    bool ok = (pmx[0] <= m_r[0] + 8.f) && (pmx[1] <= m_r[1] + 8.f) &&
              (pmx[2] <= m_r[2] + 8.f) && (pmx[3] <= m_r[3] + 8.f);
    if (!__all(ok)) {   // rare: full reduce + rescale (wave-uniform branch)
      float pm[4];
#pragma unroll
      for (int r = 0; r < 4; ++r) pm[r] = pmx[r];
#pragma unroll
      for (int off = 1; off < 16; off <<= 1)
#pragma unroll
        for (int r = 0; r < 4; ++r)
          pm[r] = fmaxf(pm[r], __shfl_xor(pm[r], off));
#pragma unroll
      for (int r = 0; r < 4; ++r) {
        float mn = fmaxf(m_r[r], pm[r]);
        float alpha = exp2f(m_r[r] - mn);
        m_r[r] = mn;
        l_r[r] *= alpha;
#pragma unroll
        for (int db = 0; db < 4; ++db) o_acc[db][r] *= alpha;
      }
    }

    float pr[4][4];
#pragma unroll
    for (int r = 0; r < 4; ++r)
#pragma unroll
      for (int f = 0; f < 4; ++f) {
        float pv = exp2f(sf[f][r] - m_r[r]);
        pr[f][r] = pv;
        l_r[r] += pv;        // per-lane partial; reduced after the loop
      }

    // ---- P -> LDS -> A-fragment ----
#pragma unroll
    for (int f = 0; f < 4; ++f)
#pragma unroll
      for (int r = 0; r < 4; ++r)
        P_lds[w][(g << 2) + r][f * 16 + l15] = f2bf(pr[f][r]);

    short8 pa0 = *(const short8*)&P_lds[w][l15][(g << 3)];
    short8 pa1 = *(const short8*)&P_lds[w][l15][32 + (g << 3)];

    // ---- PV from LDS (swizzled reads) ----
    __builtin_amdgcn_s_setprio(1);
#pragma unroll
    for (int kk = 0; kk < 2; ++kk) {
      short8 pa = kk ? pa1 : pa0;
#pragma unroll
      for (int db = 0; db < 4; ++db) {
        int row = db * 16 + l15, sw = row & 7;
        short8 bv = *(const short8*)&Vs[bi][row * 64 + ((kk * 4 + g) ^ sw) * 8];
        o_acc[db] = __builtin_amdgcn_mfma_f32_16x16x32_bf16(pa, bv, o_acc[db], 0, 0, 0);
      }
    }
    __builtin_amdgcn_s_setprio(0);
  }

  // ---- final l reduce (once) + epilogue ----
#pragma unroll
  for (int off = 1; off < 16; off <<= 1)
#pragma unroll
    for (int r = 0; r < 4; ++r)
      l_r[r] += __shfl_xor(l_r[r], off);

#pragma unroll
  for (int db = 0; db < 4; ++db)
#pragma unroll
    for (int r = 0; r < 4; ++r) {
      int s_g = q0 + (g << 2) + r;
      float v = o_acc[db][r] / l_r[r];
      O[((long)(bb * SEQ + s_g)) * 512 + h * 64 + db * 16 + l15] = f2bf(v);
    }
}

extern "C" void kernel_launch(void* const* d_in, const int* in_sizes, int n_in,
                              void* d_out, int out_size, void* d_ws, size_t ws_size,
                              hipStream_t stream) {
  const float* x  = (const float*)d_in[0];
  const float* Wq = (const float*)d_in[1];
  const float* Wk = (const float*)d_in[2];
  const float* Wv = (const float*)d_in[3];
  const float* Wo = (const float*)d_in[4];

  char* ws = (char*)d_ws;
  size_t off = 0;
  auto alloc = [&](size_t bytes) {
    void* p = ws + off;
    off += (bytes + 255) & ~(size_t)255;
    return p;
  };
  short* xb   = (short*)alloc((size_t)M_ROWS * 512 * 2);
  short* Wqkv = (short*)alloc((size_t)1536 * 512 * 2);
  short* Wob  = (short*)alloc((size_t)512 * 512 * 2);
  float* cosT = (float*)alloc((size_t)SEQ * 32 * 4);
  float* sinT = (float*)alloc((size_t)SEQ * 32 * 4);
  short* Qb   = (short*)alloc((size_t)16 * SEQ * 64 * 2);
  short* Kb   = (short*)alloc((size_t)16 * SEQ * 64 * 2);
  short* Vt   = (short*)alloc((size_t)16 * SEQ * 64 * 2);
  short* Obuf = (short*)alloc((size_t)M_ROWS * 512 * 2);

  prep_kernel<<<2048, 256, 0, stream>>>(x, Wq, Wk, Wv, Wo, xb, Wqkv, Wob, cosT, sinT);
  gemm_kernel<0><<<dim3(64, 12), 256, 0, stream>>>(xb, Wqkv, nullptr, Qb, Kb, Vt, cosT, sinT);
  attn_kernel<<<512, 512, 0, stream>>>(Qb, Kb, Vt, Obuf);
  gemm_kernel<1><<<dim3(64, 4), 256, 0, stream>>>(Obuf, Wob, (float*)d_out, nullptr, nullptr, nullptr, nullptr, nullptr);
}

// Round 11
// 206.916 us; speedup vs baseline: 1.2202x; 1.0057x over previous
//
#include <hip/hip_runtime.h>
#include <hip/hip_bf16.h>
#include <math.h>

#define D_MODEL 512
#define N_HEADS 8
#define HEAD_DIM 64
#define BATCH 2
#define SEQ 4096
#define M_ROWS (BATCH*SEQ)   // 8192

typedef __attribute__((ext_vector_type(8))) short short8;
typedef __attribute__((ext_vector_type(4))) float f32x4;

__device__ inline short f2bf(float f) {
  union { float f; unsigned u; } v; v.f = f;
  unsigned u = v.u;
  unsigned r = u + 0x7FFFu + ((u >> 16) & 1u);
  return (short)(r >> 16);
}

__device__ inline unsigned cvtpk_bf16(float lo, float hi) {
  unsigned r;
  asm("v_cvt_pk_bf16_f32 %0, %1, %2" : "=v"(r) : "v"(lo), "v"(hi));
  return r;
}

__device__ inline void gll16(const void* g, void* l) {
  __builtin_amdgcn_global_load_lds(
      (const __attribute__((address_space(1))) unsigned int*)g,
      (__attribute__((address_space(3))) unsigned int*)l, 16, 0, 0);
}

__device__ inline short8 cvt8(float4 a, float4 b) {
  short8 o;
  o[0] = f2bf(a.x); o[1] = f2bf(a.y); o[2] = f2bf(a.z); o[3] = f2bf(a.w);
  o[4] = f2bf(b.x); o[5] = f2bf(b.y); o[6] = f2bf(b.z); o[7] = f2bf(b.w);
  return o;
}

// ---------------- prep: vectorized casts + rope tables ----------------
#define XOCT (M_ROWS*D_MODEL/8)      // 524288
#define WOCT (3*D_MODEL*D_MODEL/8)   // 98304
#define OOCT (D_MODEL*D_MODEL/8)     // 32768
__global__ void prep_kernel(const float* __restrict__ x,
                            const float* __restrict__ Wq,
                            const float* __restrict__ Wk,
                            const float* __restrict__ Wv,
                            const float* __restrict__ Wo,
                            short* __restrict__ xb,
                            short* __restrict__ Wqkv,
                            short* __restrict__ Wob,
                            float* __restrict__ cosT,
                            float* __restrict__ sinT) {
  int i = blockIdx.x * blockDim.x + threadIdx.x;
  if (i < XOCT) {
    float4 a = *(const float4*)&x[i * 8];
    float4 b = *(const float4*)&x[i * 8 + 4];
    *(short8*)&xb[i * 8] = cvt8(a, b);
  }
  if (i < WOCT) {
    int e = i * 8;
    int t = e >> 18, r = e & 262143;
    const float* W = (t == 0) ? Wq : ((t == 1) ? Wk : Wv);
    float4 a = *(const float4*)&W[r];
    float4 b = *(const float4*)&W[r + 4];
    *(short8*)&Wqkv[e] = cvt8(a, b);
  }
  if (i < OOCT) {
    float4 a = *(const float4*)&Wo[i * 8];
    float4 b = *(const float4*)&Wo[i * 8 + 4];
    *(short8*)&Wob[i * 8] = cvt8(a, b);
  }
  if (i < SEQ * 32) {
    int s = i >> 5, p = i & 31;
    float e = (float)(2 * p) * (1.0f / 64.0f);
    float inv = powf(10000.0f, -e);
    float ang = (float)s * inv;
    float sv, cv;
    sincosf(ang, &sv, &cv);
    cosT[i] = cv; sinT[i] = sv;
  }
}

// ---------------- GEMM: gll16 staging + fp32-RoPE + LDS-coalesced epilogue ----
// A,B row-major [*,512] bf16. LDS tiles [128][64] unpadded, staged via
// global_load_lds with XOR-swizzled SOURCE (rule #21); reads apply same XOR.
// MODE 0: N=1536 fused QKV -> RoPE'd Q/K [BH][S][64], Vt [BH][64][S]
// MODE 1: N=512 -> fp32 d_out
template<int MODE>
__global__ __launch_bounds__(256) void gemm_kernel(const short* __restrict__ A,
                                                   const short* __restrict__ B,
                                                   float* __restrict__ out_f,
                                                   short* __restrict__ Qb,
                                                   short* __restrict__ Kb,
                                                   short* __restrict__ Vb,
                                                   const float* __restrict__ cosT,
                                                   const float* __restrict__ sinT) {
  __shared__ short smem[18432];                  // 36864 B
  short (*Cs)[136] = (short(*)[136])smem;        // epilogue reuse

  const int m0 = blockIdx.x * 128;
  const int n0 = blockIdx.y * 128;
  const int tid = threadIdx.x;
  const int lane = tid & 63, wid = tid >> 6;
  const int wm = wid >> 1, wn = wid & 1;
  const int l15 = lane & 15, g = lane >> 4;

  // staging geometry: 4 calls x 4 waves x 64 lanes x 16B = 16KB per tile
  const int srow8 = lane >> 3;                   // 0..7 within 8-row stripe
  const int sblk = (lane & 7) ^ srow8;           // swizzled 16B block

  f32x4 acc[4][4] = {};

  for (int kt = 0; kt < 512; kt += 64) {
    __syncthreads();
#pragma unroll
    for (int cc = 0; cc < 4; ++cc) {
      int r0 = (cc * 4 + wid) * 8;
      int row = r0 + srow8;
      gll16(&A[(m0 + row) * 512 + kt + sblk * 8], smem + (cc * 4 + wid) * 512);
      gll16(&B[(n0 + row) * 512 + kt + sblk * 8], smem + 8192 + (cc * 4 + wid) * 512);
    }
    __syncthreads();
#pragma unroll
    for (int kk = 0; kk < 64; kk += 32) {
      short8 a[4], b[4];
#pragma unroll
      for (int mi = 0; mi < 4; ++mi) {
        int row = wm * 64 + mi * 16 + l15;
        a[mi] = *(const short8*)&smem[row * 64 + ((((kk >> 3) + g) ^ (l15 & 7)) << 3)];
      }
#pragma unroll
      for (int ni = 0; ni < 4; ++ni) {
        int row = wn * 64 + ni * 16 + l15;
        b[ni] = *(const short8*)&smem[8192 + row * 64 + ((((kk >> 3) + g) ^ (l15 & 7)) << 3)];
      }
#pragma unroll
      for (int mi = 0; mi < 4; ++mi)
#pragma unroll
        for (int ni = 0; ni < 4; ++ni)
          acc[mi][ni] = __builtin_amdgcn_mfma_f32_16x16x32_bf16(a[mi], b[ni], acc[mi][ni], 0, 0, 0);
    }
  }

  if (MODE == 1) {
    for (int mi = 0; mi < 4; ++mi)
      for (int ni = 0; ni < 4; ++ni)
        for (int r = 0; r < 4; ++r) {
          int row_g = m0 + wm * 64 + mi * 16 + (g << 2) + r;
          int col_g = n0 + wn * 64 + ni * 16 + l15;
          out_f[row_g * 512 + col_g] = acc[mi][ni][r];
        }
    return;
  }

  // ---- MODE 0 epilogue ----
  const int t_blk = n0 >> 9;   // 0:Q 1:K 2:V (uniform per block)
  __syncthreads();             // main loop's smem reads done before overwrite

  if (t_blk < 2) {
    // RoPE in fp32 BEFORE bf16 rounding (partner = adjacent d = lane^1)
    const float qs = (t_blk == 0) ? 0.18033688011112042f : 1.0f;  // 0.125*log2e
    for (int mi = 0; mi < 4; ++mi)
      for (int ni = 0; ni < 4; ++ni)
        for (int r = 0; r < 4; ++r) {
          int lrow = wm * 64 + mi * 16 + (g << 2) + r;
          int ss = (m0 + lrow) & 4095;
          int d = (n0 + wn * 64 + ni * 16 + l15) & 63;
          int p = d >> 1;
          float c = cosT[ss * 32 + p], s = sinT[ss * 32 + p];
          float v = acc[mi][ni][r];
          float partner = __shfl_xor(v, 1);
          float res = (l15 & 1) ? (v * c + partner * s) : (v * c - partner * s);
          Cs[lrow][wn * 64 + ni * 16 + l15] = f2bf(res * qs);
        }
  } else {
    for (int mi = 0; mi < 4; ++mi)
      for (int ni = 0; ni < 4; ++ni)
        for (int r = 0; r < 4; ++r)
          Cs[wm * 64 + mi * 16 + (g << 2) + r][wn * 64 + ni * 16 + l15] =
              f2bf(acc[mi][ni][r]);
  }
  __syncthreads();

  if (t_blk < 2) {
    short* dst = (t_blk == 0) ? Qb : Kb;
#pragma unroll
    for (int it = 0; it < 8; ++it) {
      int row = (tid >> 4) + (it << 4);
      int colb = (tid & 15) << 3;
      short8 vv = *(const short8*)&Cs[row][colb];
      int row_g = m0 + row;
      int ss = row_g & 4095, bb = row_g >> 12;
      int cc = (n0 + colb) & 511;
      int h = cc >> 6, d = cc & 63;
      *(short8*)&dst[(((bb << 3) + h) * SEQ + ss) * 64 + d] = vv;
    }
  } else {
#pragma unroll
    for (int it = 0; it < 8; ++it) {
      int c = tid & 127;
      int sb = ((tid >> 7) << 3) + (it << 4);
      short8 o8;
#pragma unroll
      for (int j = 0; j < 8; ++j) o8[j] = Cs[sb + j][c];
      int row_g0 = m0 + sb;
      int ss = row_g0 & 4095, bb = row_g0 >> 12;
      int cc = (n0 + c) & 511;
      int h = cc >> 6, d = cc & 63;
      *(short8*)&Vb[((long)(((bb << 3) + h) * 64 + d)) * SEQ + ss] = o8;
    }
  }
}

// ---------------- flash attention: swapped QK^T, in-register P (T12) ----------
// Q,K: bf16 [BH=16][S=4096][64] (Q pre-scaled by 0.125*log2e)
// Vt:  bf16 [BH=16][64][S=4096]; O: bf16 [B*S][512]
// S^T = mfma(K,Q): lane owns ONE q-column (q = q0+l15) -> scalar m/l state,
// no per-chunk cross-lane reduce (defer-max vote only), P stays in registers:
// cvt_pk_bf16 pairs + 16 shfl build the PV A-fragment. No P_lds.
__global__ __launch_bounds__(512, 4) void attn_kernel(const short* __restrict__ Q,
                                                      const short* __restrict__ K,
                                                      const short* __restrict__ Vt,
                                                      short* __restrict__ O) {
  __shared__ short Ks[2][64 * 64];
  __shared__ short Vs[2][64 * 64];

  const int o = blockIdx.x;
  const int j = o >> 4;
  const int bh = o & 15;
  const int tile = (o < 256) ? (31 - j) : (j - 16);

  const int tid = threadIdx.x, lane = tid & 63, w = tid >> 6;
  const int l15 = lane & 15, g = lane >> 4;
  const long base = (long)bh * SEQ * 64;
  const long baseV = (long)bh * 64 * SEQ;
  const int bb = bh >> 3, h = bh & 7;

  const int srow = tid >> 3;
  const int sc16k = (tid & 7) ^ (srow & 7);
  short* ldsSegK0 = &Ks[0][(tid >> 6) << 9];
  short* ldsSegK1 = &Ks[1][(tid >> 6) << 9];
  short* ldsSegV0 = &Vs[0][(tid >> 6) << 9];
  short* ldsSegV1 = &Vs[1][(tid >> 6) << 9];

  const int q0 = (tile << 7) + (w << 4);
  const int nc = 2 * tile + 2;

  short8 aq0 = *(const short8*)&Q[base + (long)(q0 + l15) * 64 + (g << 3)];
  short8 aq1 = *(const short8*)&Q[base + (long)(q0 + l15) * 64 + 32 + (g << 3)];

  f32x4 o_acc[4] = {};
  float m_r = -__builtin_inff(), l_r = 0.f;

  gll16(&K[base + (long)srow * 64 + sc16k * 8], ldsSegK0);
  gll16(&Vt[baseV + (long)srow * SEQ + sc16k * 8], ldsSegV0);

  for (int c = 0; c < nc; ++c) {
    const int kv0 = c << 6;
    const int bi = c & 1;
    __syncthreads();
    if (c + 1 < nc) {
      const int nkv = (c + 1) << 6;
      short* dK = (bi ? ldsSegK0 : ldsSegK1);
      short* dV = (bi ? ldsSegV0 : ldsSegV1);
      gll16(&K[base + (long)(nkv + srow) * 64 + sc16k * 8], dK);
      gll16(&Vt[baseV + (long)srow * SEQ + nkv + sc16k * 8], dV);
    }
    if (kv0 > q0) continue;

    // ---- S^T = K Q^T : rows kv (f*16+(g<<2)+r), col q = l15 ----
    f32x4 sf[4] = {};
    __builtin_amdgcn_s_setprio(1);
#pragma unroll
    for (int f = 0; f < 4; ++f) {
      int row = f * 16 + l15, sw = row & 7;
      short8 bk0 = *(const short8*)&Ks[bi][row * 64 + ((g) ^ sw) * 8];
      short8 bk1 = *(const short8*)&Ks[bi][row * 64 + ((4 + g) ^ sw) * 8];
      sf[f] = __builtin_amdgcn_mfma_f32_16x16x32_bf16(bk0, aq0, sf[f], 0, 0, 0);
      sf[f] = __builtin_amdgcn_mfma_f32_16x16x32_bf16(bk1, aq1, sf[f], 0, 0, 0);
    }
    __builtin_amdgcn_s_setprio(0);
    if (kv0 == (q0 & ~63)) {   // diagonal chunk: causal mask (kv > q)
      int qrow = q0 + l15;
#pragma unroll
      for (int f = 0; f < 4; ++f)
#pragma unroll
        for (int r = 0; r < 4; ++r) {
          int kvc = kv0 + f * 16 + (g << 2) + r;
          if (kvc > qrow) sf[f][r] = -__builtin_inff();
        }
    }

    // ---- defer-max softmax: scalar state per lane ----
    float pmx = sf[0][0];
#pragma unroll
    for (int f = 0; f < 4; ++f)
#pragma unroll
      for (int r = 0; r < 4; ++r) pmx = fmaxf(pmx, sf[f][r]);
    if (!__all(pmx <= m_r + 8.f)) {   // rare: reduce max across 4 g-lanes
      float pm = pmx;
      pm = fmaxf(pm, __shfl_xor(pm, 16));
      pm = fmaxf(pm, __shfl_xor(pm, 32));
      float mn = fmaxf(m_r, pm);
      float alpha = exp2f(m_r - mn);
      m_r = mn;
      l_r *= alpha;
#pragma unroll
      for (int r = 0; r < 4; ++r) {
        float ar = __shfl(alpha, (g << 2) + r);
#pragma unroll
        for (int db = 0; db < 4; ++db) o_acc[db][r] *= ar;
      }
    }

    float pr[4][4];
    float s0 = 0.f;
#pragma unroll
    for (int f = 0; f < 4; ++f)
#pragma unroll
      for (int r = 0; r < 4; ++r) {
        float pv = exp2f(sf[f][r] - m_r);
        pr[f][r] = pv;
        s0 += pv;
      }
    l_r += s0;

    // ---- pack P -> bf16 pairs (kv pairs along r) ----
    unsigned pk[4][2];
#pragma unroll
    for (int f = 0; f < 4; ++f) {
      pk[f][0] = cvtpk_bf16(pr[f][0], pr[f][1]);
      pk[f][1] = cvtpk_bf16(pr[f][2], pr[f][3]);
    }
    // ---- exchange: lane (l15,g) word w <- lane l15+16*(2(g&1)+(w>>1)) ----
    unsigned paw0[4], paw1[4];
    const bool hi = (g & 2) != 0;
#pragma unroll
    for (int w2 = 0; w2 < 4; ++w2) {
      int srcl = l15 + ((2 * (g & 1) + (w2 >> 1)) << 4);
      unsigned c0 = (unsigned)__shfl((int)pk[0][w2 & 1], srcl);
      unsigned c1 = (unsigned)__shfl((int)pk[1][w2 & 1], srcl);
      unsigned c2 = (unsigned)__shfl((int)pk[2][w2 & 1], srcl);
      unsigned c3 = (unsigned)__shfl((int)pk[3][w2 & 1], srcl);
      paw0[w2] = hi ? c1 : c0;
      paw1[w2] = hi ? c3 : c2;
    }
    union { unsigned u[4]; short8 s; } u0, u1;
#pragma unroll
    for (int w2 = 0; w2 < 4; ++w2) { u0.u[w2] = paw0[w2]; u1.u[w2] = paw1[w2]; }
    short8 pa0 = u0.s, pa1 = u1.s;

    // ---- PV from LDS (swizzled reads) ----
    __builtin_amdgcn_s_setprio(1);
#pragma unroll
    for (int kk = 0; kk < 2; ++kk) {
      short8 pa = kk ? pa1 : pa0;
#pragma unroll
      for (int db = 0; db < 4; ++db) {
        int row = db * 16 + l15, sw = row & 7;
        short8 bv = *(const short8*)&Vs[bi][row * 64 + ((kk * 4 + g) ^ sw) * 8];
        o_acc[db] = __builtin_amdgcn_mfma_f32_16x16x32_bf16(pa, bv, o_acc[db], 0, 0, 0);
      }
    }
    __builtin_amdgcn_s_setprio(0);
  }

  // ---- final l reduce (q = l15 lives in 4 g-lanes) + epilogue ----
  l_r += __shfl_xor(l_r, 16);
  l_r += __shfl_xor(l_r, 32);
#pragma unroll
  for (int db = 0; db < 4; ++db)
#pragma unroll
    for (int r = 0; r < 4; ++r) {
      float lq = __shfl(l_r, (g << 2) + r);
      int s_g = q0 + (g << 2) + r;
      float v = o_acc[db][r] / lq;
      O[((long)(bb * SEQ + s_g)) * 512 + h * 64 + db * 16 + l15] = f2bf(v);
    }
}

extern "C" void kernel_launch(void* const* d_in, const int* in_sizes, int n_in,
                              void* d_out, int out_size, void* d_ws, size_t ws_size,
                              hipStream_t stream) {
  const float* x  = (const float*)d_in[0];
  const float* Wq = (const float*)d_in[1];
  const float* Wk = (const float*)d_in[2];
  const float* Wv = (const float*)d_in[3];
  const float* Wo = (const float*)d_in[4];

  char* ws = (char*)d_ws;
  size_t off = 0;
  auto alloc = [&](size_t bytes) {
    void* p = ws + off;
    off += (bytes + 255) & ~(size_t)255;
    return p;
  };
  short* xb   = (short*)alloc((size_t)M_ROWS * 512 * 2);
  short* Wqkv = (short*)alloc((size_t)1536 * 512 * 2);
  short* Wob  = (short*)alloc((size_t)512 * 512 * 2);
  float* cosT = (float*)alloc((size_t)SEQ * 32 * 4);
  float* sinT = (float*)alloc((size_t)SEQ * 32 * 4);
  short* Qb   = (short*)alloc((size_t)16 * SEQ * 64 * 2);
  short* Kb   = (short*)alloc((size_t)16 * SEQ * 64 * 2);
  short* Vt   = (short*)alloc((size_t)16 * SEQ * 64 * 2);
  short* Obuf = (short*)alloc((size_t)M_ROWS * 512 * 2);

  prep_kernel<<<2048, 256, 0, stream>>>(x, Wq, Wk, Wv, Wo, xb, Wqkv, Wob, cosT, sinT);
  gemm_kernel<0><<<dim3(64, 12), 256, 0, stream>>>(xb, Wqkv, nullptr, Qb, Kb, Vt, cosT, sinT);
  attn_kernel<<<512, 512, 0, stream>>>(Qb, Kb, Vt, Obuf);
  gemm_kernel<1><<<dim3(64, 4), 256, 0, stream>>>(Obuf, Wob, (float*)d_out, nullptr, nullptr, nullptr, nullptr, nullptr);
}